// Round 16
// baseline (177.150 us; speedup 1.0000x reference)
//
#include <hip/hip_runtime.h>

#define THREADS 256
#define SEG 4096
#define AT_LD 68
#define BN_EPS 1e-5f
#define NREP 8
#define GATHER_BLOCKS 2048

__device__ __forceinline__ float bf2f(ushort u) {
    return __uint_as_float(((unsigned)u) << 16);
}
__device__ __forceinline__ ushort f2bf(float f) {
    unsigned b = __float_as_uint(f);
    return (ushort)((b + 0x7FFFu + ((b >> 16) & 1u)) >> 16);  // RNE
}

// ---------------- init (1 block): bucket cursors to region bases, zero stats reps ----
__global__ __launch_bounds__(THREADS) void init_kernel(int* __restrict__ bcursor, int cap,
                                                       float* __restrict__ stats_rep) {
    int t = threadIdx.x;
    bcursor[t] = t * cap;
#pragma unroll
    for (int r = 0; r < 4; ++r) stats_rep[r * THREADS + t] = 0.f;
}

// ---------------- fused: partition (blocks 0..nPart) ∥ xw = x@W -> bf16 ---------------
// Partition: staging = src | dstlow<<16, fixed-capacity bucket regions (R13).
// Matmul-convert: LDS-tiled X@W (R13 matmul structure), RNE-rounded to bf16 xh.
// h = agg(x)@W = agg(x@W) by linearity -> the standalone matmul pass is deleted.
__global__ __launch_bounds__(THREADS) void conv_part_kernel(const int* __restrict__ src,
                                                            const int* __restrict__ dst, int E,
                                                            int nPart,
                                                            int* __restrict__ bcursor,
                                                            unsigned* __restrict__ staging,
                                                            const float* __restrict__ x,
                                                            const float* __restrict__ W,
                                                            ushort* __restrict__ xh, int N) {
    __shared__ __align__(16) char smem[64 * AT_LD * 4 + 64 * 64 * 4];  // union
    int bid = blockIdx.x;
    int tid = threadIdx.x;
    if (bid < nPart) {
        int* hist = (int*)smem;
        int* gbase = hist + 256;
        int* lcnt = gbase + 256;
        int nseg = (E + SEG - 1) / SEG;
        for (int seg = bid; seg < nseg; seg += nPart) {
            int base = seg * SEG;
            int lim = min(E, base + SEG);
            hist[tid] = 0;
            __syncthreads();
            for (int i = base + tid; i < lim; i += THREADS)
                atomicAdd(&hist[dst[i] >> 8], 1);
            __syncthreads();
            if (hist[tid] > 0) gbase[tid] = atomicAdd(&bcursor[tid], hist[tid]);
            lcnt[tid] = 0;
            __syncthreads();
            for (int i = base + tid; i < lim; i += THREADS) {
                int d = dst[i];
                int b = d >> 8;
                int p = gbase[b] + atomicAdd(&lcnt[b], 1);
                staging[p] = (unsigned)src[i] | ((unsigned)(d & 255) << 16);
            }
            __syncthreads();
        }
    } else {
        float* Wl = (float*)smem;           // [64*64]
        float* At = Wl + 4096;              // [64*AT_LD]
        int tile = bid - nPart;             // one 64-row tile per block
        for (int i = tid; i < 1024; i += THREADS)
            ((float4*)Wl)[i] = ((const float4*)W)[i];

        int c0 = (tid & 15) * 4;
        int r0 = (tid >> 4) * 4;
        int base = tile << 6;

        __syncthreads();
        for (int g = tid; g < 1024; g += THREADS) {
            int r = g >> 4, cc = (g & 15) << 2;
            int rowi = base + r;
            float4 v = {0.f, 0.f, 0.f, 0.f};
            if (rowi < N) v = *(const float4*)(x + ((size_t)rowi << 6) + cc);
            *(float4*)(&At[r * AT_LD + cc]) = v;
        }
        __syncthreads();

        float acc[4][4] = {};
#pragma unroll 1
        for (int k0 = 0; k0 < 64; k0 += 4) {  // rolled: full unroll spills (R4)
            float4 a[4], wf[4];
#pragma unroll
            for (int i = 0; i < 4; ++i)
                a[i] = *(const float4*)(&At[(r0 + i) * AT_LD + k0]);
#pragma unroll
            for (int q = 0; q < 4; ++q)
                wf[q] = *(const float4*)(&Wl[(k0 + q) * 64 + c0]);
#pragma unroll
            for (int i = 0; i < 4; ++i) {
                const float* ap = (const float*)&a[i];
#pragma unroll
                for (int j = 0; j < 4; ++j) {
                    acc[i][j] += ap[0] * ((const float*)&wf[0])[j] +
                                 ap[1] * ((const float*)&wf[1])[j] +
                                 ap[2] * ((const float*)&wf[2])[j] +
                                 ap[3] * ((const float*)&wf[3])[j];
                }
            }
        }

#pragma unroll
        for (int i = 0; i < 4; ++i) {
            int rowi = base + r0 + i;
            if (rowi < N) {
                ushort4 o = make_ushort4(f2bf(acc[i][0]), f2bf(acc[i][1]), f2bf(acc[i][2]),
                                         f2bf(acc[i][3]));
                *(ushort4*)(xh + ((size_t)rowi << 6) + c0) = o;
            }
        }
    }
}

// ---------------- per-bucket build: deg/offs/dinv + CSR fill, all LDS atomics --------
__global__ __launch_bounds__(THREADS) void bucket_build_kernel(const unsigned* __restrict__ staging,
                                                               const int* __restrict__ bcursor,
                                                               int cap, int N,
                                                               int* __restrict__ deg,
                                                               int* __restrict__ offs,
                                                               float* __restrict__ dinv,
                                                               int* __restrict__ csr) {
    __shared__ int hist[256];
    __shared__ int lofs[256];
    __shared__ int lcur[256];
    int tid = threadIdx.x;
    int b = blockIdx.x;
    int s = b * cap;
    int e = bcursor[b];  // final cursor = s + count(bucket b)

    hist[tid] = 0;
    __syncthreads();
    for (int i = s + tid; i < e; i += THREADS)
        atomicAdd(&hist[staging[i] >> 16], 1);
    __syncthreads();

    int v = hist[tid];
    lofs[tid] = v;
    __syncthreads();
    for (int off = 1; off < 256; off <<= 1) {
        int u = (tid >= off) ? lofs[tid - off] : 0;
        __syncthreads();
        lofs[tid] += u;
        __syncthreads();
    }
    int excl = lofs[tid] - v;

    int node = (b << 8) + tid;
    if (node < N) {
        deg[node] = v;
        offs[node] = s + excl;
        dinv[node] = rsqrtf((float)v + 1.0f);  // +1 self-loop
    }
    lcur[tid] = excl;
    __syncthreads();

    for (int i = s + tid; i < e; i += THREADS) {
        unsigned w = staging[i];
        int ln = (int)(w >> 16);
        int p = atomicAdd(&lcur[ln], 1);
        csr[s + p] = (int)(w & 0xFFFFu);
    }
}

// ---------------- pull aggregation of xw (bf16) = h, fused per-feature stats ----------
// Grid-strided (2048 blocks); wave per node; 16-deep load unroll. Stats: register
// sums -> LDS -> one global atomic per slot per block into 8-striped replicas.
__global__ __launch_bounds__(THREADS) void gather_stats_kernel(const ushort* __restrict__ xh,
                                                               const int* __restrict__ offs,
                                                               const int* __restrict__ deg,
                                                               const int* __restrict__ csr,
                                                               const float* __restrict__ dinv,
                                                               float* __restrict__ out,
                                                               float* __restrict__ stats_rep,
                                                               int N) {
    __shared__ float bred[128];
    int tid = threadIdx.x;
    int lane = tid & 63;
    if (tid < 128) bred[tid] = 0.f;
    __syncthreads();

    int wid = (blockIdx.x * THREADS + tid) >> 6;
    int nwaves = (gridDim.x * THREADS) >> 6;
    float fsum = 0.f, fsq = 0.f;

    for (int nd = wid; nd < N; nd += nwaves) {
        int node = __builtin_amdgcn_readfirstlane(nd);
        float dd = dinv[node];
        float acc = dd * bf2f(xh[((size_t)node << 6) + lane]);  // self-loop
        int start = offs[node];
        int cnt = deg[node];
        const int* __restrict__ row = csr + start;
        int j = 0;
        for (; j + 16 <= cnt; j += 16) {
            int s[16];
            float w[16];
            ushort u[16];
#pragma unroll
            for (int q = 0; q < 16; ++q) s[q] = __builtin_amdgcn_readfirstlane(row[j + q]);
#pragma unroll
            for (int q = 0; q < 16; ++q) w[q] = dinv[s[q]];
#pragma unroll
            for (int q = 0; q < 16; ++q) u[q] = xh[((size_t)s[q] << 6) + lane];
#pragma unroll
            for (int q = 0; q < 16; ++q) acc += w[q] * bf2f(u[q]);
        }
        for (; j + 4 <= cnt; j += 4) {
            int s[4];
            float w[4];
            ushort u[4];
#pragma unroll
            for (int q = 0; q < 4; ++q) s[q] = __builtin_amdgcn_readfirstlane(row[j + q]);
#pragma unroll
            for (int q = 0; q < 4; ++q) w[q] = dinv[s[q]];
#pragma unroll
            for (int q = 0; q < 4; ++q) u[q] = xh[((size_t)s[q] << 6) + lane];
#pragma unroll
            for (int q = 0; q < 4; ++q) acc += w[q] * bf2f(u[q]);
        }
        for (; j < cnt; ++j) {
            int s = __builtin_amdgcn_readfirstlane(row[j]);
            acc += dinv[s] * bf2f(xh[((size_t)s << 6) + lane]);
        }
        float h = dd * acc;
        out[((size_t)node << 6) + lane] = h;
        fsum += h;
        fsq += h * h;
    }

    atomicAdd(&bred[lane], fsum);
    atomicAdd(&bred[64 + lane], fsq);
    __syncthreads();
    if (tid < 128)
        atomicAdd(&stats_rep[((blockIdx.x & (NREP - 1)) << 7) + tid], bred[tid]);
}

// ---------------- BN + ReLU in place (sums NREP stat replicas) ----------------
__global__ __launch_bounds__(THREADS) void bn_relu_kernel(float* __restrict__ io,
                                                          const float* __restrict__ stats_rep,
                                                          int nrep,
                                                          const float* __restrict__ gamma,
                                                          const float* __restrict__ beta,
                                                          int n4, float invN) {
    int t = blockIdx.x * blockDim.x + threadIdx.x;
    if (t >= n4) return;
    int f0 = (t & 15) * 4;
    float4 v = ((const float4*)io)[t];
    float vv[4] = {v.x, v.y, v.z, v.w};
    float o[4];
#pragma unroll
    for (int j = 0; j < 4; ++j) {
        int f = f0 + j;
        float s1 = 0.f, s2 = 0.f;
        for (int r = 0; r < nrep; ++r) {
            s1 += stats_rep[(r << 7) + f];
            s2 += stats_rep[(r << 7) + 64 + f];
        }
        float mean = s1 * invN;
        float var = s2 * invN - mean * mean;
        float scale = gamma[f] * rsqrtf(var + BN_EPS);
        float shift = beta[f] - mean * scale;
        float y = vv[j] * scale + shift;
        o[j] = y > 0.f ? y : 0.f;
    }
    float4 r = {o[0], o[1], o[2], o[3]};
    ((float4*)io)[t] = r;
}

// ================= fallback (push path) kernels =================
__global__ __launch_bounds__(THREADS) void deg_kernel(const int* __restrict__ dst, int E,
                                                      int* __restrict__ deg) {
    int e = blockIdx.x * blockDim.x + threadIdx.x;
    if (e < E) atomicAdd(&deg[dst[e]], 1);
}

__global__ __launch_bounds__(THREADS) void dinv_kernel(const int* __restrict__ deg,
                                                       float* __restrict__ dinv, int N) {
    int i = blockIdx.x * blockDim.x + threadIdx.x;
    if (i < N) dinv[i] = rsqrtf((float)deg[i] + 1.0f);
}

__global__ __launch_bounds__(THREADS) void selfloop_kernel(const float4* __restrict__ x4,
                                                           const float* __restrict__ dinv,
                                                           float4* __restrict__ out4, int n4) {
    int t = blockIdx.x * blockDim.x + threadIdx.x;
    if (t >= n4) return;
    int node = t >> 4;
    float s = dinv[node];
    s *= s;
    float4 v = x4[t];
    v.x *= s; v.y *= s; v.z *= s; v.w *= s;
    out4[t] = v;
}

__global__ __launch_bounds__(THREADS) void scatter_kernel(const int* __restrict__ src,
                                                          const int* __restrict__ dst, int E,
                                                          const float* __restrict__ x,
                                                          const float* __restrict__ dinv,
                                                          float* __restrict__ out) {
    int lane = threadIdx.x & 63;
    int wave = (blockIdx.x * blockDim.x + threadIdx.x) >> 6;
    int nwaves = (gridDim.x * blockDim.x) >> 6;
    for (int e = wave; e < E; e += nwaves) {
        int s = src[e];
        int d = dst[e];
        float nrm = dinv[s] * dinv[d];
        atomicAdd(&out[d * 64 + lane], x[s * 64 + lane] * nrm);
    }
}

__global__ __launch_bounds__(THREADS) void matmul_stats_kernel(float* __restrict__ io,
                                                               const float* __restrict__ W,
                                                               float* __restrict__ stats, int N) {
    __shared__ float Wl[64 * 64];
    __shared__ float At[64 * AT_LD];
    __shared__ float bred[128];
    int tid = threadIdx.x;

    for (int i = tid; i < 1024; i += THREADS)
        ((float4*)Wl)[i] = ((const float4*)W)[i];

    int c0 = (tid & 15) * 4;
    int r0 = (tid >> 4) * 4;
    int ntiles = (N + 63) >> 6;
    float sums[4] = {0.f, 0.f, 0.f, 0.f};
    float sqs[4] = {0.f, 0.f, 0.f, 0.f};

    for (int tile = blockIdx.x; tile < ntiles; tile += gridDim.x) {
        int base = tile << 6;
        __syncthreads();
        for (int g = tid; g < 1024; g += THREADS) {
            int r = g >> 4, cc = (g & 15) << 2;
            int rowi = base + r;
            float4 v = {0.f, 0.f, 0.f, 0.f};
            if (rowi < N) v = *(const float4*)(io + ((size_t)rowi << 6) + cc);
            *(float4*)(&At[r * AT_LD + cc]) = v;
        }
        __syncthreads();

        float acc[4][4] = {};
#pragma unroll 1
        for (int k0 = 0; k0 < 64; k0 += 4) {
            float4 a[4], wf[4];
#pragma unroll
            for (int i = 0; i < 4; ++i)
                a[i] = *(const float4*)(&At[(r0 + i) * AT_LD + k0]);
#pragma unroll
            for (int q = 0; q < 4; ++q)
                wf[q] = *(const float4*)(&Wl[(k0 + q) * 64 + c0]);
#pragma unroll
            for (int i = 0; i < 4; ++i) {
                const float* ap = (const float*)&a[i];
#pragma unroll
                for (int j = 0; j < 4; ++j) {
                    acc[i][j] += ap[0] * ((const float*)&wf[0])[j] +
                                 ap[1] * ((const float*)&wf[1])[j] +
                                 ap[2] * ((const float*)&wf[2])[j] +
                                 ap[3] * ((const float*)&wf[3])[j];
                }
            }
        }

#pragma unroll
        for (int i = 0; i < 4; ++i) {
            int rowi = base + r0 + i;
            if (rowi < N) {
                float4 o = {acc[i][0], acc[i][1], acc[i][2], acc[i][3]};
                *(float4*)(io + ((size_t)rowi << 6) + c0) = o;
#pragma unroll
                for (int j = 0; j < 4; ++j) {
                    sums[j] += acc[i][j];
                    sqs[j] += acc[i][j] * acc[i][j];
                }
            }
        }
    }

    __syncthreads();
    if (tid < 128) bred[tid] = 0.f;
    __syncthreads();
#pragma unroll
    for (int j = 0; j < 4; ++j) {
        atomicAdd(&bred[c0 + j], sums[j]);
        atomicAdd(&bred[64 + c0 + j], sqs[j]);
    }
    __syncthreads();
    if (tid < 128) atomicAdd(&stats[tid], bred[tid]);
}

extern "C" void kernel_launch(void* const* d_in, const int* in_sizes, int n_in,
                              void* d_out, int out_size, void* d_ws, size_t ws_size,
                              hipStream_t stream) {
    const float* x     = (const float*)d_in[0];
    const int*   edges = (const int*)d_in[1];
    const float* W     = (const float*)d_in[2];
    // d_in[3] = b cancels exactly in training-mode BN
    const float* gamma = (const float*)d_in[4];
    const float* beta  = (const float*)d_in[5];
    float* out = (float*)d_out;

    const int N = in_sizes[0] / 64;
    const int E = in_sizes[1] / 2;
    const int* src = edges;
    const int* dst = edges + E;
    const int n4 = N * 16;

    const int nb = (N + 255) >> 8;                     // buckets
    const int avg = (E + nb - 1) / nb;
    const int cap = avg + (avg >> 2) + 512;            // ~8-sigma slack for Binomial load

    char* ws = (char*)d_ws;
    // layout: stats_rep f32[1024] | bcursor[256] | deg[N] | offs[N] | dinv[N] |
    //         csr[nb*cap] | staging[nb*cap] | xh[64N ushort]
    size_t off_stats   = 0;
    size_t off_bcursor = 4096;
    size_t off_deg     = off_bcursor + 1024;
    size_t off_offs    = off_deg + (size_t)4 * N;
    size_t off_dinv    = off_offs + (size_t)4 * N;
    size_t off_csr     = off_dinv + (size_t)4 * N;
    size_t off_staging = off_csr + (size_t)4 * nb * cap;
    size_t off_xh      = (off_staging + (size_t)4 * nb * cap + 15) & ~(size_t)15;
    size_t need        = off_xh + (size_t)128 * N;

    if (ws_size >= need && N <= 65536) {
        float* stats_rep = (float*)(ws + off_stats);
        int*   bcursor   = (int*)(ws + off_bcursor);
        int*   deg       = (int*)(ws + off_deg);
        int*   offs      = (int*)(ws + off_offs);
        float* dinv      = (float*)(ws + off_dinv);
        int*   csr       = (int*)(ws + off_csr);
        unsigned* staging = (unsigned*)(ws + off_staging);
        ushort* xh       = (ushort*)(ws + off_xh);

        int nseg = (E + SEG - 1) / SEG;
        int nPart = nseg < 1024 ? nseg : 1024;
        int ntiles = (N + 63) >> 6;

        init_kernel<<<1, THREADS, 0, stream>>>(bcursor, cap, stats_rep);
        conv_part_kernel<<<nPart + ntiles, THREADS, 0, stream>>>(
            src, dst, E, nPart, bcursor, staging, x, W, xh, N);
        bucket_build_kernel<<<nb, THREADS, 0, stream>>>(staging, bcursor, cap, N, deg, offs,
                                                        dinv, csr);
        gather_stats_kernel<<<GATHER_BLOCKS, THREADS, 0, stream>>>(xh, offs, deg, csr, dinv,
                                                                   out, stats_rep, N);
        bn_relu_kernel<<<(n4 + THREADS - 1) / THREADS, THREADS, 0, stream>>>(
            out, stats_rep, NREP, gamma, beta, n4, 1.0f / (float)N);
    } else {
        // fallback: push path (ws: deg[N] | stats[128] | dinv[N])
        int*   deg   = (int*)ws;
        float* stats = (float*)(ws + (size_t)N * 4);
        float* dinv  = (float*)(ws + (size_t)N * 4 + 512);

        hipMemsetAsync(ws, 0, (size_t)N * 4 + 512, stream);
        deg_kernel<<<(E + THREADS - 1) / THREADS, THREADS, 0, stream>>>(dst, E, deg);
        dinv_kernel<<<(N + THREADS - 1) / THREADS, THREADS, 0, stream>>>(deg, dinv, N);
        selfloop_kernel<<<(n4 + THREADS - 1) / THREADS, THREADS, 0, stream>>>(
            (const float4*)x, dinv, (float4*)out, n4);
        scatter_kernel<<<1024, THREADS, 0, stream>>>(src, dst, E, x, dinv, out);
        matmul_stats_kernel<<<512, THREADS, 0, stream>>>(out, W, stats, N);
        bn_relu_kernel<<<(n4 + THREADS - 1) / THREADS, THREADS, 0, stream>>>(
            out, stats, 1, gamma, beta, n4, 1.0f / (float)N);
    }
}

// Round 17
// 117.987 us; speedup vs baseline: 1.5014x; 1.5014x over previous
//
#include <hip/hip_runtime.h>

#define THREADS 256
#define SEG 4096
#define AT_LD 68
#define BN_EPS 1e-5f
#define NREP 8
#define GATHER_BLOCKS 2048

__device__ __forceinline__ float bf2f(ushort u) {
    return __uint_as_float(((unsigned)u) << 16);
}
__device__ __forceinline__ ushort f2bf(float f) {
    unsigned b = __float_as_uint(f);
    return (ushort)((b + 0x7FFFu + ((b >> 16) & 1u)) >> 16);  // RNE
}

// ---------------- init (1 block): bucket cursors to region bases, zero stats reps ----
__global__ __launch_bounds__(THREADS) void init_kernel(int* __restrict__ bcursor, int cap,
                                                       float* __restrict__ stats_rep) {
    int t = threadIdx.x;
    bcursor[t] = t * cap;
#pragma unroll
    for (int r = 0; r < 4; ++r) stats_rep[r * THREADS + t] = 0.f;
}

// ---------------- fused: partition (blocks 0..nPart) ∥ xw = x@W -> bf16 ---------------
// h = agg(x)@W = agg(x@W) by linearity -> the standalone matmul pass is deleted (R16).
__global__ __launch_bounds__(THREADS) void conv_part_kernel(const int* __restrict__ src,
                                                            const int* __restrict__ dst, int E,
                                                            int nPart,
                                                            int* __restrict__ bcursor,
                                                            unsigned* __restrict__ staging,
                                                            const float* __restrict__ x,
                                                            const float* __restrict__ W,
                                                            ushort* __restrict__ xh, int N) {
    __shared__ __align__(16) char smem[64 * AT_LD * 4 + 64 * 64 * 4];  // union
    int bid = blockIdx.x;
    int tid = threadIdx.x;
    if (bid < nPart) {
        int* hist = (int*)smem;
        int* gbase = hist + 256;
        int* lcnt = gbase + 256;
        int nseg = (E + SEG - 1) / SEG;
        for (int seg = bid; seg < nseg; seg += nPart) {
            int base = seg * SEG;
            int lim = min(E, base + SEG);
            hist[tid] = 0;
            __syncthreads();
            for (int i = base + tid; i < lim; i += THREADS)
                atomicAdd(&hist[dst[i] >> 8], 1);
            __syncthreads();
            if (hist[tid] > 0) gbase[tid] = atomicAdd(&bcursor[tid], hist[tid]);
            lcnt[tid] = 0;
            __syncthreads();
            for (int i = base + tid; i < lim; i += THREADS) {
                int d = dst[i];
                int b = d >> 8;
                int p = gbase[b] + atomicAdd(&lcnt[b], 1);
                staging[p] = (unsigned)src[i] | ((unsigned)(d & 255) << 16);
            }
            __syncthreads();
        }
    } else {
        float* Wl = (float*)smem;           // [64*64]
        float* At = Wl + 4096;              // [64*AT_LD]
        int tile = bid - nPart;             // one 64-row tile per block
        for (int i = tid; i < 1024; i += THREADS)
            ((float4*)Wl)[i] = ((const float4*)W)[i];

        int c0 = (tid & 15) * 4;
        int r0 = (tid >> 4) * 4;
        int base = tile << 6;

        __syncthreads();
        for (int g = tid; g < 1024; g += THREADS) {
            int r = g >> 4, cc = (g & 15) << 2;
            int rowi = base + r;
            float4 v = {0.f, 0.f, 0.f, 0.f};
            if (rowi < N) v = *(const float4*)(x + ((size_t)rowi << 6) + cc);
            *(float4*)(&At[r * AT_LD + cc]) = v;
        }
        __syncthreads();

        float acc[4][4] = {};
#pragma unroll 1
        for (int k0 = 0; k0 < 64; k0 += 4) {  // rolled: full unroll spills (R4)
            float4 a[4], wf[4];
#pragma unroll
            for (int i = 0; i < 4; ++i)
                a[i] = *(const float4*)(&At[(r0 + i) * AT_LD + k0]);
#pragma unroll
            for (int q = 0; q < 4; ++q)
                wf[q] = *(const float4*)(&Wl[(k0 + q) * 64 + c0]);
#pragma unroll
            for (int i = 0; i < 4; ++i) {
                const float* ap = (const float*)&a[i];
#pragma unroll
                for (int j = 0; j < 4; ++j) {
                    acc[i][j] += ap[0] * ((const float*)&wf[0])[j] +
                                 ap[1] * ((const float*)&wf[1])[j] +
                                 ap[2] * ((const float*)&wf[2])[j] +
                                 ap[3] * ((const float*)&wf[3])[j];
                }
            }
        }

#pragma unroll
        for (int i = 0; i < 4; ++i) {
            int rowi = base + r0 + i;
            if (rowi < N) {
                ushort4 o = make_ushort4(f2bf(acc[i][0]), f2bf(acc[i][1]), f2bf(acc[i][2]),
                                         f2bf(acc[i][3]));
                *(ushort4*)(xh + ((size_t)rowi << 6) + c0) = o;
            }
        }
    }
}

// ---------------- per-bucket build: deg/offs/dinv + CSR fill, all LDS atomics --------
__global__ __launch_bounds__(THREADS) void bucket_build_kernel(const unsigned* __restrict__ staging,
                                                               const int* __restrict__ bcursor,
                                                               int cap, int N,
                                                               int* __restrict__ deg,
                                                               int* __restrict__ offs,
                                                               float* __restrict__ dinv,
                                                               int* __restrict__ csr) {
    __shared__ int hist[256];
    __shared__ int lofs[256];
    __shared__ int lcur[256];
    int tid = threadIdx.x;
    int b = blockIdx.x;
    int s = b * cap;
    int e = bcursor[b];  // final cursor = s + count(bucket b)

    hist[tid] = 0;
    __syncthreads();
    for (int i = s + tid; i < e; i += THREADS)
        atomicAdd(&hist[staging[i] >> 16], 1);
    __syncthreads();

    int v = hist[tid];
    lofs[tid] = v;
    __syncthreads();
    for (int off = 1; off < 256; off <<= 1) {
        int u = (tid >= off) ? lofs[tid - off] : 0;
        __syncthreads();
        lofs[tid] += u;
        __syncthreads();
    }
    int excl = lofs[tid] - v;

    int node = (b << 8) + tid;
    if (node < N) {
        deg[node] = v;
        offs[node] = s + excl;
        dinv[node] = rsqrtf((float)v + 1.0f);  // +1 self-loop
    }
    lcur[tid] = excl;
    __syncthreads();

    for (int i = s + tid; i < e; i += THREADS) {
        unsigned w = staging[i];
        int ln = (int)(w >> 16);
        int p = atomicAdd(&lcur[ln], 1);
        csr[s + p] = (int)(w & 0xFFFFu);
    }
}

// ---------------- pull aggregation of xw (bf16) = h, fused per-feature stats ----------
__global__ __launch_bounds__(THREADS) void gather_stats_kernel(const ushort* __restrict__ xh,
                                                               const int* __restrict__ offs,
                                                               const int* __restrict__ deg,
                                                               const int* __restrict__ csr,
                                                               const float* __restrict__ dinv,
                                                               float* __restrict__ out,
                                                               float* __restrict__ stats_rep,
                                                               int N) {
    __shared__ float bred[128];
    int tid = threadIdx.x;
    int lane = tid & 63;
    if (tid < 128) bred[tid] = 0.f;
    __syncthreads();

    int wid = (blockIdx.x * THREADS + tid) >> 6;
    int nwaves = (gridDim.x * THREADS) >> 6;
    float fsum = 0.f, fsq = 0.f;

    for (int nd = wid; nd < N; nd += nwaves) {
        int node = __builtin_amdgcn_readfirstlane(nd);
        float dd = dinv[node];
        float acc = dd * bf2f(xh[((size_t)node << 6) + lane]);  // self-loop
        int start = offs[node];
        int cnt = deg[node];
        const int* __restrict__ row = csr + start;
        int j = 0;
        for (; j + 16 <= cnt; j += 16) {
            int s[16];
            float w[16];
            ushort u[16];
#pragma unroll
            for (int q = 0; q < 16; ++q) s[q] = __builtin_amdgcn_readfirstlane(row[j + q]);
#pragma unroll
            for (int q = 0; q < 16; ++q) w[q] = dinv[s[q]];
#pragma unroll
            for (int q = 0; q < 16; ++q) u[q] = xh[((size_t)s[q] << 6) + lane];
#pragma unroll
            for (int q = 0; q < 16; ++q) acc += w[q] * bf2f(u[q]);
        }
        for (; j + 4 <= cnt; j += 4) {
            int s[4];
            float w[4];
            ushort u[4];
#pragma unroll
            for (int q = 0; q < 4; ++q) s[q] = __builtin_amdgcn_readfirstlane(row[j + q]);
#pragma unroll
            for (int q = 0; q < 4; ++q) w[q] = dinv[s[q]];
#pragma unroll
            for (int q = 0; q < 4; ++q) u[q] = xh[((size_t)s[q] << 6) + lane];
#pragma unroll
            for (int q = 0; q < 4; ++q) acc += w[q] * bf2f(u[q]);
        }
        for (; j < cnt; ++j) {
            int s = __builtin_amdgcn_readfirstlane(row[j]);
            acc += dinv[s] * bf2f(xh[((size_t)s << 6) + lane]);
        }
        float h = dd * acc;
        out[((size_t)node << 6) + lane] = h;
        fsum += h;
        fsq += h * h;
    }

    atomicAdd(&bred[lane], fsum);
    atomicAdd(&bred[64 + lane], fsq);
    __syncthreads();
    if (tid < 128)
        atomicAdd(&stats_rep[((blockIdx.x & (NREP - 1)) << 7) + tid], bred[tid]);
}

// ---------------- BN + ReLU: per-block LDS stage of scale/shift, then stream ----------
// R16 bug: per-thread runtime-nrep loop = 64 serial global loads -> 70us latency-bound.
// Fix: threads 0..127 reduce the NREP replicas (compile-time unroll, coalesced),
// compute scale/shift into LDS once per block; main loop reads LDS.
__global__ __launch_bounds__(THREADS) void bn_relu_kernel(float* __restrict__ io,
                                                          const float* __restrict__ stats_rep,
                                                          const float* __restrict__ gamma,
                                                          const float* __restrict__ beta,
                                                          int n4, float invN) {
    __shared__ float sc[64];
    __shared__ float sh[64];
    int tid = threadIdx.x;
    if (tid < 64) {
        float s1 = 0.f, s2 = 0.f;
#pragma unroll
        for (int r = 0; r < NREP; ++r) {
            s1 += stats_rep[(r << 7) + tid];
            s2 += stats_rep[(r << 7) + 64 + tid];
        }
        float mean = s1 * invN;
        float var = s2 * invN - mean * mean;
        float scale = gamma[tid] * rsqrtf(var + BN_EPS);
        sc[tid] = scale;
        sh[tid] = beta[tid] - mean * scale;
    }
    __syncthreads();

    int t = blockIdx.x * blockDim.x + tid;
    if (t >= n4) return;
    int f0 = (t & 15) * 4;
    float4 v = ((const float4*)io)[t];
    float vv[4] = {v.x, v.y, v.z, v.w};
    float o[4];
#pragma unroll
    for (int j = 0; j < 4; ++j) {
        float y = vv[j] * sc[f0 + j] + sh[f0 + j];
        o[j] = y > 0.f ? y : 0.f;
    }
    float4 r = {o[0], o[1], o[2], o[3]};
    ((float4*)io)[t] = r;
}

// ================= fallback (push path) kernels =================
__global__ __launch_bounds__(THREADS) void deg_kernel(const int* __restrict__ dst, int E,
                                                      int* __restrict__ deg) {
    int e = blockIdx.x * blockDim.x + threadIdx.x;
    if (e < E) atomicAdd(&deg[dst[e]], 1);
}

__global__ __launch_bounds__(THREADS) void dinv_kernel(const int* __restrict__ deg,
                                                       float* __restrict__ dinv, int N) {
    int i = blockIdx.x * blockDim.x + threadIdx.x;
    if (i < N) dinv[i] = rsqrtf((float)deg[i] + 1.0f);
}

__global__ __launch_bounds__(THREADS) void selfloop_kernel(const float4* __restrict__ x4,
                                                           const float* __restrict__ dinv,
                                                           float4* __restrict__ out4, int n4) {
    int t = blockIdx.x * blockDim.x + threadIdx.x;
    if (t >= n4) return;
    int node = t >> 4;
    float s = dinv[node];
    s *= s;
    float4 v = x4[t];
    v.x *= s; v.y *= s; v.z *= s; v.w *= s;
    out4[t] = v;
}

__global__ __launch_bounds__(THREADS) void scatter_kernel(const int* __restrict__ src,
                                                          const int* __restrict__ dst, int E,
                                                          const float* __restrict__ x,
                                                          const float* __restrict__ dinv,
                                                          float* __restrict__ out) {
    int lane = threadIdx.x & 63;
    int wave = (blockIdx.x * blockDim.x + threadIdx.x) >> 6;
    int nwaves = (gridDim.x * blockDim.x) >> 6;
    for (int e = wave; e < E; e += nwaves) {
        int s = src[e];
        int d = dst[e];
        float nrm = dinv[s] * dinv[d];
        atomicAdd(&out[d * 64 + lane], x[s * 64 + lane] * nrm);
    }
}

__global__ __launch_bounds__(THREADS) void matmul_stats_kernel(float* __restrict__ io,
                                                               const float* __restrict__ W,
                                                               float* __restrict__ stats, int N) {
    __shared__ float Wl[64 * 64];
    __shared__ float At[64 * AT_LD];
    __shared__ float bred[128];
    int tid = threadIdx.x;

    for (int i = tid; i < 1024; i += THREADS)
        ((float4*)Wl)[i] = ((const float4*)W)[i];

    int c0 = (tid & 15) * 4;
    int r0 = (tid >> 4) * 4;
    int ntiles = (N + 63) >> 6;
    float sums[4] = {0.f, 0.f, 0.f, 0.f};
    float sqs[4] = {0.f, 0.f, 0.f, 0.f};

    for (int tile = blockIdx.x; tile < ntiles; tile += gridDim.x) {
        int base = tile << 6;
        __syncthreads();
        for (int g = tid; g < 1024; g += THREADS) {
            int r = g >> 4, cc = (g & 15) << 2;
            int rowi = base + r;
            float4 v = {0.f, 0.f, 0.f, 0.f};
            if (rowi < N) v = *(const float4*)(io + ((size_t)rowi << 6) + cc);
            *(float4*)(&At[r * AT_LD + cc]) = v;
        }
        __syncthreads();

        float acc[4][4] = {};
#pragma unroll 1
        for (int k0 = 0; k0 < 64; k0 += 4) {
            float4 a[4], wf[4];
#pragma unroll
            for (int i = 0; i < 4; ++i)
                a[i] = *(const float4*)(&At[(r0 + i) * AT_LD + k0]);
#pragma unroll
            for (int q = 0; q < 4; ++q)
                wf[q] = *(const float4*)(&Wl[(k0 + q) * 64 + c0]);
#pragma unroll
            for (int i = 0; i < 4; ++i) {
                const float* ap = (const float*)&a[i];
#pragma unroll
                for (int j = 0; j < 4; ++j) {
                    acc[i][j] += ap[0] * ((const float*)&wf[0])[j] +
                                 ap[1] * ((const float*)&wf[1])[j] +
                                 ap[2] * ((const float*)&wf[2])[j] +
                                 ap[3] * ((const float*)&wf[3])[j];
                }
            }
        }

#pragma unroll
        for (int i = 0; i < 4; ++i) {
            int rowi = base + r0 + i;
            if (rowi < N) {
                float4 o = {acc[i][0], acc[i][1], acc[i][2], acc[i][3]};
                *(float4*)(io + ((size_t)rowi << 6) + c0) = o;
#pragma unroll
                for (int j = 0; j < 4; ++j) {
                    sums[j] += acc[i][j];
                    sqs[j] += acc[i][j] * acc[i][j];
                }
            }
        }
    }

    __syncthreads();
    if (tid < 128) bred[tid] = 0.f;
    __syncthreads();
#pragma unroll
    for (int j = 0; j < 4; ++j) {
        atomicAdd(&bred[c0 + j], sums[j]);
        atomicAdd(&bred[64 + c0 + j], sqs[j]);
    }
    __syncthreads();
    if (tid < 128) atomicAdd(&stats[tid], bred[tid]);
}

extern "C" void kernel_launch(void* const* d_in, const int* in_sizes, int n_in,
                              void* d_out, int out_size, void* d_ws, size_t ws_size,
                              hipStream_t stream) {
    const float* x     = (const float*)d_in[0];
    const int*   edges = (const int*)d_in[1];
    const float* W     = (const float*)d_in[2];
    // d_in[3] = b cancels exactly in training-mode BN
    const float* gamma = (const float*)d_in[4];
    const float* beta  = (const float*)d_in[5];
    float* out = (float*)d_out;

    const int N = in_sizes[0] / 64;
    const int E = in_sizes[1] / 2;
    const int* src = edges;
    const int* dst = edges + E;
    const int n4 = N * 16;

    const int nb = (N + 255) >> 8;                     // buckets
    const int avg = (E + nb - 1) / nb;
    const int cap = avg + (avg >> 2) + 512;            // ~8-sigma slack for Binomial load

    char* ws = (char*)d_ws;
    // layout: stats_rep f32[1024] | bcursor[256] | deg[N] | offs[N] | dinv[N] |
    //         csr[nb*cap] | staging[nb*cap] | xh[64N ushort]
    size_t off_stats   = 0;
    size_t off_bcursor = 4096;
    size_t off_deg     = off_bcursor + 1024;
    size_t off_offs    = off_deg + (size_t)4 * N;
    size_t off_dinv    = off_offs + (size_t)4 * N;
    size_t off_csr     = off_dinv + (size_t)4 * N;
    size_t off_staging = off_csr + (size_t)4 * nb * cap;
    size_t off_xh      = (off_staging + (size_t)4 * nb * cap + 15) & ~(size_t)15;
    size_t need        = off_xh + (size_t)128 * N;

    if (ws_size >= need && N <= 65536) {
        float* stats_rep = (float*)(ws + off_stats);
        int*   bcursor   = (int*)(ws + off_bcursor);
        int*   deg       = (int*)(ws + off_deg);
        int*   offs      = (int*)(ws + off_offs);
        float* dinv      = (float*)(ws + off_dinv);
        int*   csr       = (int*)(ws + off_csr);
        unsigned* staging = (unsigned*)(ws + off_staging);
        ushort* xh       = (ushort*)(ws + off_xh);

        int nseg = (E + SEG - 1) / SEG;
        int nPart = nseg < 1024 ? nseg : 1024;
        int ntiles = (N + 63) >> 6;

        init_kernel<<<1, THREADS, 0, stream>>>(bcursor, cap, stats_rep);
        conv_part_kernel<<<nPart + ntiles, THREADS, 0, stream>>>(
            src, dst, E, nPart, bcursor, staging, x, W, xh, N);
        bucket_build_kernel<<<nb, THREADS, 0, stream>>>(staging, bcursor, cap, N, deg, offs,
                                                        dinv, csr);
        gather_stats_kernel<<<GATHER_BLOCKS, THREADS, 0, stream>>>(xh, offs, deg, csr, dinv,
                                                                   out, stats_rep, N);
        bn_relu_kernel<<<(n4 + THREADS - 1) / THREADS, THREADS, 0, stream>>>(
            out, stats_rep, gamma, beta, n4, 1.0f / (float)N);
    } else {
        // fallback: push path (ws: deg[N] | stats[128, via stats_rep slot 0] | dinv[N])
        int*   deg   = (int*)ws;
        float* stats = (float*)(ws + (size_t)N * 4);
        float* dinv  = (float*)(ws + (size_t)N * 4 + 4096);

        hipMemsetAsync(ws, 0, (size_t)N * 4 + 4096, stream);
        deg_kernel<<<(E + THREADS - 1) / THREADS, THREADS, 0, stream>>>(dst, E, deg);
        dinv_kernel<<<(N + THREADS - 1) / THREADS, THREADS, 0, stream>>>(deg, dinv, N);
        selfloop_kernel<<<(n4 + THREADS - 1) / THREADS, THREADS, 0, stream>>>(
            (const float4*)x, dinv, (float4*)out, n4);
        scatter_kernel<<<1024, THREADS, 0, stream>>>(src, dst, E, x, dinv, out);
        matmul_stats_kernel<<<512, THREADS, 0, stream>>>(out, W, stats, N);
        // stats laid out as single 128-float block = replica 0; others zero
        bn_relu_kernel<<<(n4 + THREADS - 1) / THREADS, THREADS, 0, stream>>>(
            out, stats, gamma, beta, n4, 1.0f / (float)N);
    }
}

// Round 18
// 102.534 us; speedup vs baseline: 1.7277x; 1.1507x over previous
//
#include <hip/hip_runtime.h>

#define THREADS 256
#define SEG 4096
#define AT_LD 68
#define BN_EPS 1e-5f
#define NREP 8

__device__ __forceinline__ float bf2f(ushort u) {
    return __uint_as_float(((unsigned)u) << 16);
}
__device__ __forceinline__ ushort f2bf(float f) {
    unsigned b = __float_as_uint(f);
    return (ushort)((b + 0x7FFFu + ((b >> 16) & 1u)) >> 16);  // RNE
}

// ---------------- init (1 block): bucket cursors to region bases, zero stats reps ----
__global__ __launch_bounds__(THREADS) void init_kernel(int* __restrict__ bcursor, int cap,
                                                       float* __restrict__ stats_rep) {
    int t = threadIdx.x;
    bcursor[t] = t * cap;
#pragma unroll
    for (int r = 0; r < 4; ++r) stats_rep[r * THREADS + t] = 0.f;
}

// ---------------- fused: partition (blocks 0..nPart) ∥ xw = x@W -> bf16 ---------------
// h = agg(x)@W = agg(x@W) by linearity -> the standalone matmul pass is deleted (R16).
__global__ __launch_bounds__(THREADS) void conv_part_kernel(const int* __restrict__ src,
                                                            const int* __restrict__ dst, int E,
                                                            int nPart,
                                                            int* __restrict__ bcursor,
                                                            unsigned* __restrict__ staging,
                                                            const float* __restrict__ x,
                                                            const float* __restrict__ W,
                                                            ushort* __restrict__ xh, int N) {
    __shared__ __align__(16) char smem[64 * AT_LD * 4 + 64 * 64 * 4];  // union
    int bid = blockIdx.x;
    int tid = threadIdx.x;
    if (bid < nPart) {
        int* hist = (int*)smem;
        int* gbase = hist + 256;
        int* lcnt = gbase + 256;
        int nseg = (E + SEG - 1) / SEG;
        for (int seg = bid; seg < nseg; seg += nPart) {
            int base = seg * SEG;
            int lim = min(E, base + SEG);
            hist[tid] = 0;
            __syncthreads();
            for (int i = base + tid; i < lim; i += THREADS)
                atomicAdd(&hist[dst[i] >> 8], 1);
            __syncthreads();
            if (hist[tid] > 0) gbase[tid] = atomicAdd(&bcursor[tid], hist[tid]);
            lcnt[tid] = 0;
            __syncthreads();
            for (int i = base + tid; i < lim; i += THREADS) {
                int d = dst[i];
                int b = d >> 8;
                int p = gbase[b] + atomicAdd(&lcnt[b], 1);
                staging[p] = (unsigned)src[i] | ((unsigned)(d & 255) << 16);
            }
            __syncthreads();
        }
    } else {
        float* Wl = (float*)smem;           // [64*64]
        float* At = Wl + 4096;              // [64*AT_LD]
        int tile = bid - nPart;             // one 64-row tile per block
        for (int i = tid; i < 1024; i += THREADS)
            ((float4*)Wl)[i] = ((const float4*)W)[i];

        int c0 = (tid & 15) * 4;
        int r0 = (tid >> 4) * 4;
        int base = tile << 6;

        __syncthreads();
        for (int g = tid; g < 1024; g += THREADS) {
            int r = g >> 4, cc = (g & 15) << 2;
            int rowi = base + r;
            float4 v = {0.f, 0.f, 0.f, 0.f};
            if (rowi < N) v = *(const float4*)(x + ((size_t)rowi << 6) + cc);
            *(float4*)(&At[r * AT_LD + cc]) = v;
        }
        __syncthreads();

        float acc[4][4] = {};
#pragma unroll 1
        for (int k0 = 0; k0 < 64; k0 += 4) {  // rolled: full unroll spills (R4)
            float4 a[4], wf[4];
#pragma unroll
            for (int i = 0; i < 4; ++i)
                a[i] = *(const float4*)(&At[(r0 + i) * AT_LD + k0]);
#pragma unroll
            for (int q = 0; q < 4; ++q)
                wf[q] = *(const float4*)(&Wl[(k0 + q) * 64 + c0]);
#pragma unroll
            for (int i = 0; i < 4; ++i) {
                const float* ap = (const float*)&a[i];
#pragma unroll
                for (int j = 0; j < 4; ++j) {
                    acc[i][j] += ap[0] * ((const float*)&wf[0])[j] +
                                 ap[1] * ((const float*)&wf[1])[j] +
                                 ap[2] * ((const float*)&wf[2])[j] +
                                 ap[3] * ((const float*)&wf[3])[j];
                }
            }
        }

#pragma unroll
        for (int i = 0; i < 4; ++i) {
            int rowi = base + r0 + i;
            if (rowi < N) {
                ushort4 o = make_ushort4(f2bf(acc[i][0]), f2bf(acc[i][1]), f2bf(acc[i][2]),
                                         f2bf(acc[i][3]));
                *(ushort4*)(xh + ((size_t)rowi << 6) + c0) = o;
            }
        }
    }
}

// ---------------- per-bucket build: deg/offs/dinv + CSR fill, all LDS atomics --------
__global__ __launch_bounds__(THREADS) void bucket_build_kernel(const unsigned* __restrict__ staging,
                                                               const int* __restrict__ bcursor,
                                                               int cap, int N,
                                                               int* __restrict__ deg,
                                                               int* __restrict__ offs,
                                                               float* __restrict__ dinv,
                                                               int* __restrict__ csr) {
    __shared__ int hist[256];
    __shared__ int lofs[256];
    __shared__ int lcur[256];
    int tid = threadIdx.x;
    int b = blockIdx.x;
    int s = b * cap;
    int e = bcursor[b];  // final cursor = s + count(bucket b)

    hist[tid] = 0;
    __syncthreads();
    for (int i = s + tid; i < e; i += THREADS)
        atomicAdd(&hist[staging[i] >> 16], 1);
    __syncthreads();

    int v = hist[tid];
    lofs[tid] = v;
    __syncthreads();
    for (int off = 1; off < 256; off <<= 1) {
        int u = (tid >= off) ? lofs[tid - off] : 0;
        __syncthreads();
        lofs[tid] += u;
        __syncthreads();
    }
    int excl = lofs[tid] - v;

    int node = (b << 8) + tid;
    if (node < N) {
        deg[node] = v;
        offs[node] = s + excl;
        dinv[node] = rsqrtf((float)v + 1.0f);  // +1 self-loop
    }
    lcur[tid] = excl;
    __syncthreads();

    for (int i = s + tid; i < e; i += THREADS) {
        unsigned w = staging[i];
        int ln = (int)(w >> 16);
        int p = atomicAdd(&lcur[ln], 1);
        csr[s + p] = (int)(w & 0xFFFFu);
    }
}

// ---------------- pull aggregation of xw (bf16): one wave per node (R15 form) ---------
__global__ __launch_bounds__(THREADS) void gather_bf16_kernel(const ushort* __restrict__ xh,
                                                              const int* __restrict__ offs,
                                                              const int* __restrict__ deg,
                                                              const int* __restrict__ csr,
                                                              const float* __restrict__ dinv,
                                                              float* __restrict__ out, int N) {
    int lane = threadIdx.x & 63;
    int node = __builtin_amdgcn_readfirstlane(
        (int)((blockIdx.x * blockDim.x + threadIdx.x) >> 6));
    if (node >= N) return;
    float dd = dinv[node];
    float acc = dd * bf2f(xh[((size_t)node << 6) + lane]);  // self-loop
    int start = offs[node];
    int cnt = deg[node];
    const int* __restrict__ row = csr + start;
    int j = 0;
    for (; j + 16 <= cnt; j += 16) {
        int s[16];
        float w[16];
        ushort u[16];
#pragma unroll
        for (int q = 0; q < 16; ++q) s[q] = __builtin_amdgcn_readfirstlane(row[j + q]);
#pragma unroll
        for (int q = 0; q < 16; ++q) w[q] = dinv[s[q]];
#pragma unroll
        for (int q = 0; q < 16; ++q) u[q] = xh[((size_t)s[q] << 6) + lane];
#pragma unroll
        for (int q = 0; q < 16; ++q) acc += w[q] * bf2f(u[q]);
    }
    for (; j + 4 <= cnt; j += 4) {
        int s[4];
        float w[4];
        ushort u[4];
#pragma unroll
        for (int q = 0; q < 4; ++q) s[q] = __builtin_amdgcn_readfirstlane(row[j + q]);
#pragma unroll
        for (int q = 0; q < 4; ++q) w[q] = dinv[s[q]];
#pragma unroll
        for (int q = 0; q < 4; ++q) u[q] = xh[((size_t)s[q] << 6) + lane];
#pragma unroll
        for (int q = 0; q < 4; ++q) acc += w[q] * bf2f(u[q]);
    }
    for (; j < cnt; ++j) {
        int s = __builtin_amdgcn_readfirstlane(row[j]);
        acc += dinv[s] * bf2f(xh[((size_t)s << 6) + lane]);
    }
    out[((size_t)node << 6) + lane] = dd * acc;
}

// ---------------- streaming per-feature stats over out (f32 h) ----------------
// Sequential float4 reads; feature group (t&15)*4 is loop-invariant since the
// grid stride is a multiple of 16 float4s. Register sums -> LDS -> 1 atomic per
// slot per block into 8-striped replicas.
__global__ __launch_bounds__(THREADS) void stats_kernel(const float4* __restrict__ out4,
                                                        int n4,
                                                        float* __restrict__ stats_rep) {
    __shared__ float bred[128];
    int tid = threadIdx.x;
    if (tid < 128) bred[tid] = 0.f;
    __syncthreads();

    int f0 = (tid & 15) * 4;
    float sums[4] = {0.f, 0.f, 0.f, 0.f};
    float sqs[4] = {0.f, 0.f, 0.f, 0.f};
    int stride = gridDim.x * THREADS;  // multiple of 16 -> t&15 invariant
    for (int t = blockIdx.x * THREADS + tid; t < n4; t += stride) {
        float4 v = out4[t];
        const float* vv = (const float*)&v;
#pragma unroll
        for (int j = 0; j < 4; ++j) {
            sums[j] += vv[j];
            sqs[j] += vv[j] * vv[j];
        }
    }
#pragma unroll
    for (int j = 0; j < 4; ++j) {
        atomicAdd(&bred[f0 + j], sums[j]);
        atomicAdd(&bred[64 + f0 + j], sqs[j]);
    }
    __syncthreads();
    if (tid < 128)
        atomicAdd(&stats_rep[((blockIdx.x & (NREP - 1)) << 7) + tid], bred[tid]);
}

// ---------------- BN + ReLU: per-block LDS stage of scale/shift, then stream ----------
__global__ __launch_bounds__(THREADS) void bn_relu_kernel(float* __restrict__ io,
                                                          const float* __restrict__ stats_rep,
                                                          const float* __restrict__ gamma,
                                                          const float* __restrict__ beta,
                                                          int n4, float invN) {
    __shared__ float sc[64];
    __shared__ float sh[64];
    int tid = threadIdx.x;
    if (tid < 64) {
        float s1 = 0.f, s2 = 0.f;
#pragma unroll
        for (int r = 0; r < NREP; ++r) {
            s1 += stats_rep[(r << 7) + tid];
            s2 += stats_rep[(r << 7) + 64 + tid];
        }
        float mean = s1 * invN;
        float var = s2 * invN - mean * mean;
        float scale = gamma[tid] * rsqrtf(var + BN_EPS);
        sc[tid] = scale;
        sh[tid] = beta[tid] - mean * scale;
    }
    __syncthreads();

    int t = blockIdx.x * blockDim.x + tid;
    if (t >= n4) return;
    int f0 = (t & 15) * 4;
    float4 v = ((const float4*)io)[t];
    float vv[4] = {v.x, v.y, v.z, v.w};
    float o[4];
#pragma unroll
    for (int j = 0; j < 4; ++j) {
        float y = vv[j] * sc[f0 + j] + sh[f0 + j];
        o[j] = y > 0.f ? y : 0.f;
    }
    float4 r = {o[0], o[1], o[2], o[3]};
    ((float4*)io)[t] = r;
}

// ================= fallback (push path) kernels =================
__global__ __launch_bounds__(THREADS) void deg_kernel(const int* __restrict__ dst, int E,
                                                      int* __restrict__ deg) {
    int e = blockIdx.x * blockDim.x + threadIdx.x;
    if (e < E) atomicAdd(&deg[dst[e]], 1);
}

__global__ __launch_bounds__(THREADS) void dinv_kernel(const int* __restrict__ deg,
                                                       float* __restrict__ dinv, int N) {
    int i = blockIdx.x * blockDim.x + threadIdx.x;
    if (i < N) dinv[i] = rsqrtf((float)deg[i] + 1.0f);
}

__global__ __launch_bounds__(THREADS) void selfloop_kernel(const float4* __restrict__ x4,
                                                           const float* __restrict__ dinv,
                                                           float4* __restrict__ out4, int n4) {
    int t = blockIdx.x * blockDim.x + threadIdx.x;
    if (t >= n4) return;
    int node = t >> 4;
    float s = dinv[node];
    s *= s;
    float4 v = x4[t];
    v.x *= s; v.y *= s; v.z *= s; v.w *= s;
    out4[t] = v;
}

__global__ __launch_bounds__(THREADS) void scatter_kernel(const int* __restrict__ src,
                                                          const int* __restrict__ dst, int E,
                                                          const float* __restrict__ x,
                                                          const float* __restrict__ dinv,
                                                          float* __restrict__ out) {
    int lane = threadIdx.x & 63;
    int wave = (blockIdx.x * blockDim.x + threadIdx.x) >> 6;
    int nwaves = (gridDim.x * blockDim.x) >> 6;
    for (int e = wave; e < E; e += nwaves) {
        int s = src[e];
        int d = dst[e];
        float nrm = dinv[s] * dinv[d];
        atomicAdd(&out[d * 64 + lane], x[s * 64 + lane] * nrm);
    }
}

__global__ __launch_bounds__(THREADS) void matmul_stats_kernel(float* __restrict__ io,
                                                               const float* __restrict__ W,
                                                               float* __restrict__ stats, int N) {
    __shared__ float Wl[64 * 64];
    __shared__ float At[64 * AT_LD];
    __shared__ float bred[128];
    int tid = threadIdx.x;

    for (int i = tid; i < 1024; i += THREADS)
        ((float4*)Wl)[i] = ((const float4*)W)[i];

    int c0 = (tid & 15) * 4;
    int r0 = (tid >> 4) * 4;
    int ntiles = (N + 63) >> 6;
    float sums[4] = {0.f, 0.f, 0.f, 0.f};
    float sqs[4] = {0.f, 0.f, 0.f, 0.f};

    for (int tile = blockIdx.x; tile < ntiles; tile += gridDim.x) {
        int base = tile << 6;
        __syncthreads();
        for (int g = tid; g < 1024; g += THREADS) {
            int r = g >> 4, cc = (g & 15) << 2;
            int rowi = base + r;
            float4 v = {0.f, 0.f, 0.f, 0.f};
            if (rowi < N) v = *(const float4*)(io + ((size_t)rowi << 6) + cc);
            *(float4*)(&At[r * AT_LD + cc]) = v;
        }
        __syncthreads();

        float acc[4][4] = {};
#pragma unroll 1
        for (int k0 = 0; k0 < 64; k0 += 4) {
            float4 a[4], wf[4];
#pragma unroll
            for (int i = 0; i < 4; ++i)
                a[i] = *(const float4*)(&At[(r0 + i) * AT_LD + k0]);
#pragma unroll
            for (int q = 0; q < 4; ++q)
                wf[q] = *(const float4*)(&Wl[(k0 + q) * 64 + c0]);
#pragma unroll
            for (int i = 0; i < 4; ++i) {
                const float* ap = (const float*)&a[i];
#pragma unroll
                for (int j = 0; j < 4; ++j) {
                    acc[i][j] += ap[0] * ((const float*)&wf[0])[j] +
                                 ap[1] * ((const float*)&wf[1])[j] +
                                 ap[2] * ((const float*)&wf[2])[j] +
                                 ap[3] * ((const float*)&wf[3])[j];
                }
            }
        }

#pragma unroll
        for (int i = 0; i < 4; ++i) {
            int rowi = base + r0 + i;
            if (rowi < N) {
                float4 o = {acc[i][0], acc[i][1], acc[i][2], acc[i][3]};
                *(float4*)(io + ((size_t)rowi << 6) + c0) = o;
#pragma unroll
                for (int j = 0; j < 4; ++j) {
                    sums[j] += acc[i][j];
                    sqs[j] += acc[i][j] * acc[i][j];
                }
            }
        }
    }

    __syncthreads();
    if (tid < 128) bred[tid] = 0.f;
    __syncthreads();
#pragma unroll
    for (int j = 0; j < 4; ++j) {
        atomicAdd(&bred[c0 + j], sums[j]);
        atomicAdd(&bred[64 + c0 + j], sqs[j]);
    }
    __syncthreads();
    if (tid < 128) atomicAdd(&stats[tid], bred[tid]);
}

extern "C" void kernel_launch(void* const* d_in, const int* in_sizes, int n_in,
                              void* d_out, int out_size, void* d_ws, size_t ws_size,
                              hipStream_t stream) {
    const float* x     = (const float*)d_in[0];
    const int*   edges = (const int*)d_in[1];
    const float* W     = (const float*)d_in[2];
    // d_in[3] = b cancels exactly in training-mode BN
    const float* gamma = (const float*)d_in[4];
    const float* beta  = (const float*)d_in[5];
    float* out = (float*)d_out;

    const int N = in_sizes[0] / 64;
    const int E = in_sizes[1] / 2;
    const int* src = edges;
    const int* dst = edges + E;
    const int n4 = N * 16;

    const int nb = (N + 255) >> 8;                     // buckets
    const int avg = (E + nb - 1) / nb;
    const int cap = avg + (avg >> 2) + 512;            // ~8-sigma slack for Binomial load

    char* ws = (char*)d_ws;
    // layout: stats_rep f32[1024] | bcursor[256] | deg[N] | offs[N] | dinv[N] |
    //         csr[nb*cap] | staging[nb*cap] | xh[64N ushort]
    size_t off_stats   = 0;
    size_t off_bcursor = 4096;
    size_t off_deg     = off_bcursor + 1024;
    size_t off_offs    = off_deg + (size_t)4 * N;
    size_t off_dinv    = off_offs + (size_t)4 * N;
    size_t off_csr     = off_dinv + (size_t)4 * N;
    size_t off_staging = off_csr + (size_t)4 * nb * cap;
    size_t off_xh      = (off_staging + (size_t)4 * nb * cap + 15) & ~(size_t)15;
    size_t need        = off_xh + (size_t)128 * N;

    if (ws_size >= need && N <= 65536) {
        float* stats_rep = (float*)(ws + off_stats);
        int*   bcursor   = (int*)(ws + off_bcursor);
        int*   deg       = (int*)(ws + off_deg);
        int*   offs      = (int*)(ws + off_offs);
        float* dinv      = (float*)(ws + off_dinv);
        int*   csr       = (int*)(ws + off_csr);
        unsigned* staging = (unsigned*)(ws + off_staging);
        ushort* xh       = (ushort*)(ws + off_xh);

        int nseg = (E + SEG - 1) / SEG;
        int nPart = nseg < 1024 ? nseg : 1024;
        int ntiles = (N + 63) >> 6;

        init_kernel<<<1, THREADS, 0, stream>>>(bcursor, cap, stats_rep);
        conv_part_kernel<<<nPart + ntiles, THREADS, 0, stream>>>(
            src, dst, E, nPart, bcursor, staging, x, W, xh, N);
        bucket_build_kernel<<<nb, THREADS, 0, stream>>>(staging, bcursor, cap, N, deg, offs,
                                                        dinv, csr);
        gather_bf16_kernel<<<(N * 64 + THREADS - 1) / THREADS, THREADS, 0, stream>>>(
            xh, offs, deg, csr, dinv, out, N);
        stats_kernel<<<1024, THREADS, 0, stream>>>((const float4*)out, n4, stats_rep);
        bn_relu_kernel<<<(n4 + THREADS - 1) / THREADS, THREADS, 0, stream>>>(
            out, stats_rep, gamma, beta, n4, 1.0f / (float)N);
    } else {
        // fallback: push path (ws: deg[N] | stats[1024 f32, replica 0 used] | dinv[N])
        int*   deg   = (int*)ws;
        float* stats = (float*)(ws + (size_t)N * 4);
        float* dinv  = (float*)(ws + (size_t)N * 4 + 4096);

        hipMemsetAsync(ws, 0, (size_t)N * 4 + 4096, stream);
        deg_kernel<<<(E + THREADS - 1) / THREADS, THREADS, 0, stream>>>(dst, E, deg);
        dinv_kernel<<<(N + THREADS - 1) / THREADS, THREADS, 0, stream>>>(deg, dinv, N);
        selfloop_kernel<<<(n4 + THREADS - 1) / THREADS, THREADS, 0, stream>>>(
            (const float4*)x, dinv, (float4*)out, n4);
        scatter_kernel<<<1024, THREADS, 0, stream>>>(src, dst, E, x, dinv, out);
        matmul_stats_kernel<<<512, THREADS, 0, stream>>>(out, W, stats, N);
        // stats layout = replica 0; replicas 1..7 zeroed by memset
        bn_relu_kernel<<<(n4 + THREADS - 1) / THREADS, THREADS, 0, stream>>>(
            out, stats, gamma, beta, n4, 1.0f / (float)N);
    }
}